// Round 2
// baseline (4062.765 us; speedup 1.0000x reference)
//
#include <hip/hip_runtime.h>
#include <hip/hip_bf16.h>

#define NN 32768
#define EE 262144
#define FD 128
#define NL 64

// NOTE: harness delivers integer inputs as int32 (even though reference is
// int64) — reading as long long in R1 caused OOB atomics and a core dump.

// ---------- setup: degree count ----------
__global__ __launch_bounds__(256) void k_deg(const int* __restrict__ dst,
                                             int* __restrict__ cnt) {
    int e = blockIdx.x * 256 + threadIdx.x;
    if (e < EE) atomicAdd(&cnt[dst[e]], 1);
}

__global__ __launch_bounds__(256) void k_dinv(const int* __restrict__ cnt,
                                              float* __restrict__ dinv) {
    int i = blockIdx.x * 256 + threadIdx.x;
    if (i < NN) dinv[i] = rsqrtf((float)cnt[i] + 1.0f);  // +1 self loop; always > 0
}

// single-block exclusive scan of cnt[NN] -> offs[NN+1]
__global__ __launch_bounds__(1024) void k_scan(const int* __restrict__ cnt,
                                               int* __restrict__ offs) {
    __shared__ int wsum[16];
    int tid = threadIdx.x;
    int base = tid * 32;
    int local[32];
    int s = 0;
#pragma unroll
    for (int i = 0; i < 32; i++) { local[i] = s; s += cnt[base + i]; }
    int lane = tid & 63, wv = tid >> 6;
    int x = s;
#pragma unroll
    for (int off = 1; off < 64; off <<= 1) {
        int y = __shfl_up(x, off);
        if (lane >= off) x += y;
    }
    if (lane == 63) wsum[wv] = x;
    __syncthreads();
    if (tid == 0) {
        int t = 0;
        for (int i = 0; i < 16; i++) { int v = wsum[i]; wsum[i] = t; t += v; }
        offs[NN] = t;
    }
    __syncthreads();
    int excl = wsum[wv] + x - s;  // exclusive prefix of this thread's chunk
#pragma unroll
    for (int i = 0; i < 32; i++) offs[base + i] = excl + local[i];
}

__global__ __launch_bounds__(256) void k_fill(const int* __restrict__ src,
                                              const int* __restrict__ dst,
                                              const float* __restrict__ dinv,
                                              const int* __restrict__ offs,
                                              int* __restrict__ cursor,
                                              int* __restrict__ col,
                                              float* __restrict__ wgt) {
    int e = blockIdx.x * 256 + threadIdx.x;
    if (e >= EE) return;
    int s = src[e], d = dst[e];
    int slot = atomicAdd(&cursor[d], 1);
    int p = offs[d] + slot;
    col[p] = s;
    wgt[p] = dinv[s] * dinv[d];
}

// ---------- dense: C[NN x 128] = A[NN x 128] @ B[128 x 128], fp32 ----------
// 128x128 tile per block, BK=32, 256 threads, 8x8 outputs/thread.
__global__ __launch_bounds__(256) void k_gemm(const float* __restrict__ A,
                                              const float* __restrict__ B,
                                              float* __restrict__ C) {
    __shared__ float As[32][132];  // transposed A tile, +4 pad
    __shared__ float Bs[32][132];
    int tid = threadIdx.x;
    int ty = tid >> 4, tx = tid & 15;
    int row0 = blockIdx.x * 128;
    float acc[8][8];
#pragma unroll
    for (int i = 0; i < 8; i++)
#pragma unroll
        for (int j = 0; j < 8; j++) acc[i][j] = 0.f;

    for (int k0 = 0; k0 < FD; k0 += 32) {
#pragma unroll
        for (int t = 0; t < 4; t++) {
            int id = tid + t * 256;          // 0..1023
            int r = id >> 3;                  // 0..127 (A row in tile)
            int kc = (id & 7) << 2;           // 0..28
            float4 v = *(const float4*)(A + (size_t)(row0 + r) * FD + k0 + kc);
            As[kc + 0][r] = v.x;
            As[kc + 1][r] = v.y;
            As[kc + 2][r] = v.z;
            As[kc + 3][r] = v.w;
            int rb = id >> 5;                 // 0..31 (B k-row)
            int cb = (id & 31) << 2;          // 0..124
            float4 w = *(const float4*)(B + (size_t)(k0 + rb) * FD + cb);
            *(float4*)&Bs[rb][cb] = w;
        }
        __syncthreads();
#pragma unroll
        for (int k = 0; k < 32; k++) {
            float a[8], b[8];
            *(float4*)&a[0] = *(const float4*)&As[k][ty * 8];
            *(float4*)&a[4] = *(const float4*)&As[k][ty * 8 + 4];
            *(float4*)&b[0] = *(const float4*)&Bs[k][tx * 8];
            *(float4*)&b[4] = *(const float4*)&Bs[k][tx * 8 + 4];
#pragma unroll
            for (int i = 0; i < 8; i++)
#pragma unroll
                for (int j = 0; j < 8; j++) acc[i][j] += a[i] * b[j];
        }
        __syncthreads();
    }
#pragma unroll
    for (int i = 0; i < 8; i++) {
        float* cp = C + (size_t)(row0 + ty * 8 + i) * FD + tx * 8;
        *(float4*)cp = *(float4*)&acc[i][0];
        *(float4*)(cp + 4) = *(float4*)&acc[i][4];
    }
}

// ---------- sparse aggregation + bias + relu; one wave per node ----------
__global__ __launch_bounds__(256) void k_agg(const float* __restrict__ hw,
                                             const int* __restrict__ offs,
                                             const int* __restrict__ col,
                                             const float* __restrict__ wgt,
                                             const float* __restrict__ dinv,
                                             const float* __restrict__ bias,
                                             float* __restrict__ hout) {
    int gw = (blockIdx.x * 256 + threadIdx.x) >> 6;
    int lane = threadIdx.x & 63;
    if (gw >= NN) return;
    float di = dinv[gw];
    float2 sv = *(const float2*)(hw + (size_t)gw * FD + lane * 2);
    float ax = di * di * sv.x, ay = di * di * sv.y;  // self loop
    int b = offs[gw], e = offs[gw + 1];
    for (int i = b; i < e; i++) {
        int s = col[i];
        float w = wgt[i];
        float2 v = *(const float2*)(hw + (size_t)s * FD + lane * 2);
        ax += w * v.x;
        ay += w * v.y;
    }
    float2 bb = *(const float2*)(bias + lane * 2);
    ax += bb.x; ay += bb.y;
    ax = ax > 0.f ? ax : 0.f;
    ay = ay > 0.f ? ay : 0.f;
    *(float2*)(hout + (size_t)gw * FD + lane * 2) = make_float2(ax, ay);
}

// ---------- residual + classifier: out = (h + x) @ cls_w + cls_b ----------
__global__ __launch_bounds__(256) void k_cls(const float* __restrict__ h,
                                             const float* __restrict__ x,
                                             const float* __restrict__ cw,
                                             const float* __restrict__ cb,
                                             float* __restrict__ out) {
    int gw = (blockIdx.x * 256 + threadIdx.x) >> 6;
    int lane = threadIdx.x & 63;
    if (gw >= NN) return;
    float2 hv = *(const float2*)(h + (size_t)gw * FD + lane * 2);
    float2 xv = *(const float2*)(x + (size_t)gw * FD + lane * 2);
    float sx = hv.x + xv.x, sy = hv.y + xv.y;
    float4 w0 = *(const float4*)(cw + (lane * 2) * 4);
    float4 w1 = *(const float4*)(cw + (lane * 2 + 1) * 4);
    float p0 = sx * w0.x + sy * w1.x;
    float p1 = sx * w0.y + sy * w1.y;
    float p2 = sx * w0.z + sy * w1.z;
    float p3 = sx * w0.w + sy * w1.w;
#pragma unroll
    for (int off = 32; off > 0; off >>= 1) {
        p0 += __shfl_down(p0, off);
        p1 += __shfl_down(p1, off);
        p2 += __shfl_down(p2, off);
        p3 += __shfl_down(p3, off);
    }
    if (lane == 0) {
        float4 r = make_float4(p0 + cb[0], p1 + cb[1], p2 + cb[2], p3 + cb[3]);
        *(float4*)(out + (size_t)gw * 4) = r;
    }
}

extern "C" void kernel_launch(void* const* d_in, const int* in_sizes, int n_in,
                              void* d_out, int out_size, void* d_ws, size_t ws_size,
                              hipStream_t stream) {
    const float* x       = (const float*)d_in[0];
    const int* ei        = (const int*)d_in[1];       // [2][EE], int32 (harness converts)
    const float* weights = (const float*)d_in[2];     // [64][128][128]
    const float* biases  = (const float*)d_in[3];     // [64][128]
    const float* cls_w   = (const float*)d_in[4];     // [128][4]
    const float* cls_b   = (const float*)d_in[5];     // [4]
    float* out = (float*)d_out;

    char* ws = (char*)d_ws;
    size_t off = 0;
    auto alloc = [&](size_t bytes) -> void* {
        off = (off + 255) & ~(size_t)255;
        void* p = ws + off;
        off += bytes;
        return p;
    };
    int*   cnt    = (int*)alloc((size_t)NN * 4);
    int*   cursor = (int*)alloc((size_t)NN * 4);
    float* dinv   = (float*)alloc((size_t)NN * 4);
    int*   offs   = (int*)alloc((size_t)(NN + 1) * 4);
    int*   col    = (int*)alloc((size_t)EE * 4);
    float* wgt    = (float*)alloc((size_t)EE * 4);
    float* hw     = (float*)alloc((size_t)NN * FD * 4);
    float* h0     = (float*)alloc((size_t)NN * FD * 4);
    float* h1     = (float*)alloc((size_t)NN * FD * 4);

    const int* srcv = ei;
    const int* dstv = ei + EE;

    hipMemsetAsync(cnt, 0, (size_t)NN * 4, stream);
    hipMemsetAsync(cursor, 0, (size_t)NN * 4, stream);
    k_deg<<<EE / 256, 256, 0, stream>>>(dstv, cnt);
    k_dinv<<<NN / 256, 256, 0, stream>>>(cnt, dinv);
    k_scan<<<1, 1024, 0, stream>>>(cnt, offs);
    k_fill<<<EE / 256, 256, 0, stream>>>(srcv, dstv, dinv, offs, cursor, col, wgt);

    const float* hin = x;
    for (int l = 0; l < NL; l++) {
        float* hout = (l & 1) ? h1 : h0;
        k_gemm<<<NN / 128, 256, 0, stream>>>(hin, weights + (size_t)l * FD * FD, hw);
        k_agg<<<NN * 64 / 256, 256, 0, stream>>>(hw, offs, col, wgt, dinv,
                                                 biases + (size_t)l * FD, hout);
        hin = hout;
    }
    k_cls<<<NN * 64 / 256, 256, 0, stream>>>(hin, x, cls_w, cls_b, out);
}

// Round 3
// 2965.577 us; speedup vs baseline: 1.3700x; 1.3700x over previous
//
#include <hip/hip_runtime.h>
#include <hip/hip_bf16.h>

#define NN 32768
#define EE 262144
#define FD 128
#define NL 64

typedef short v8s __attribute__((ext_vector_type(8)));
typedef float v4f __attribute__((ext_vector_type(4)));

__device__ __forceinline__ unsigned short f2bf(float x) {
    unsigned u = __builtin_bit_cast(unsigned, x);
    u += 0x7fffu + ((u >> 16) & 1u);
    return (unsigned short)(u >> 16);
}
__device__ __forceinline__ float bf2f(unsigned short h) {
    unsigned u = ((unsigned)h) << 16;
    return __builtin_bit_cast(float, u);
}

// ---------- setup: degree count ----------
__global__ __launch_bounds__(256) void k_deg(const int* __restrict__ dst,
                                             int* __restrict__ cnt) {
    int e = blockIdx.x * 256 + threadIdx.x;
    if (e < EE) atomicAdd(&cnt[dst[e]], 1);
}

__global__ __launch_bounds__(256) void k_dinv(const int* __restrict__ cnt,
                                              float* __restrict__ dinv) {
    int i = blockIdx.x * 256 + threadIdx.x;
    if (i < NN) dinv[i] = rsqrtf((float)cnt[i] + 1.0f);
}

// single-block exclusive scan of cnt[NN] -> offs[NN+1]
__global__ __launch_bounds__(1024) void k_scan(const int* __restrict__ cnt,
                                               int* __restrict__ offs) {
    __shared__ int wsum[16];
    int tid = threadIdx.x;
    int base = tid * 32;
    int local[32];
    int s = 0;
#pragma unroll
    for (int i = 0; i < 32; i++) { local[i] = s; s += cnt[base + i]; }
    int lane = tid & 63, wv = tid >> 6;
    int x = s;
#pragma unroll
    for (int off = 1; off < 64; off <<= 1) {
        int y = __shfl_up(x, off);
        if (lane >= off) x += y;
    }
    if (lane == 63) wsum[wv] = x;
    __syncthreads();
    if (tid == 0) {
        int t = 0;
        for (int i = 0; i < 16; i++) { int v = wsum[i]; wsum[i] = t; t += v; }
        offs[NN] = t;
    }
    __syncthreads();
    int excl = wsum[wv] + x - s;
#pragma unroll
    for (int i = 0; i < 32; i++) offs[base + i] = excl + local[i];
}

__global__ __launch_bounds__(256) void k_fill(const int* __restrict__ src,
                                              const int* __restrict__ dst,
                                              const float* __restrict__ dinv,
                                              const int* __restrict__ offs,
                                              int* __restrict__ cursor,
                                              int* __restrict__ col,
                                              float* __restrict__ wgt) {
    int e = blockIdx.x * 256 + threadIdx.x;
    if (e >= EE) return;
    int s = src[e], d = dst[e];
    int slot = atomicAdd(&cursor[d], 1);
    int p = offs[d] + slot;
    col[p] = s;
    wgt[p] = dinv[s] * dinv[d];
}

// ---------- weight split: fp32 W -> bf16 hi/lo in MFMA B-fragment order ----
// Fragment order: [l][kstep(4)][ntile(8)][lane(64)][j(8)]
// maps W[l][k][n] with k = ks*32 + (lane>>4)*8 + j, n = nt*16 + (lane&15).
__global__ __launch_bounds__(256) void k_wsplit(const float* __restrict__ W,
                                                unsigned short* __restrict__ Whi,
                                                unsigned short* __restrict__ Wlo) {
    int t = blockIdx.x * 256 + threadIdx.x;  // 0 .. 64*4*8*64-1 = 131071
    int l = t >> 11;
    int rem = t & 2047;
    int ks = rem >> 9;
    int rem2 = rem & 511;
    int nt = rem2 >> 6;
    int L = rem2 & 63;
    const float* Wl = W + (size_t)l * FD * FD;
    int kbase = ks * 32 + ((L >> 4) << 3);
    int n = nt * 16 + (L & 15);
    v8s hv, lv;
#pragma unroll
    for (int j = 0; j < 8; j++) {
        float w = Wl[(size_t)(kbase + j) * FD + n];
        unsigned short h = f2bf(w);
        hv[j] = (short)h;
        lv[j] = (short)f2bf(w - bf2f(h));
    }
    size_t o = (size_t)t * 8;
    *(v8s*)(Whi + o) = hv;
    *(v8s*)(Wlo + o) = lv;
}

// ---------- dense: Chw[bf16, NNx128] = A[fp32] @ W, split-bf16 MFMA --------
// Block: 128 rows x 128 cols, 256 threads = 4 waves in 2x2; wave = 64x64
// (4x4 tiles of 16x16x32 MFMA). 3 MFMAs per tile per K-step (hi*hi, lo*hi,
// hi*lo) gives ~fp32 accuracy. B fragments load straight from global (L2-hot).
__global__ __launch_bounds__(256) void k_gemm_mfma(const float* __restrict__ A,
                                                   const unsigned short* __restrict__ Whi,
                                                   const unsigned short* __restrict__ Wlo,
                                                   unsigned short* __restrict__ Chw) {
    __shared__ unsigned short smem[17408];  // staging 2x8KB; epilogue 128x136
    int tid = threadIdx.x;
    int lane = tid & 63;
    int w = tid >> 6;
    int wm = w >> 1, wn = w & 1;
    int row0 = blockIdx.x * 128;

    int r = tid >> 1;             // 0..127: A row in tile
    int chalf = (tid & 1) * 16;   // 0 or 16: k offset within BK=32
    const float* Arow = A + (size_t)(row0 + r) * FD + chalf;

    v4f acc[4][4];
#pragma unroll
    for (int i = 0; i < 4; i++)
#pragma unroll
        for (int j = 0; j < 4; j++) acc[i][j] = (v4f){0.f, 0.f, 0.f, 0.f};

    float4 areg[4];
#pragma unroll
    for (int c = 0; c < 4; c++) areg[c] = *(const float4*)(Arow + c * 4);

    for (int ks = 0; ks < 4; ks++) {
        // split fp32 -> hi/lo bf16, store in A-fragment order
        float f[16];
        *(float4*)&f[0] = areg[0]; *(float4*)&f[4] = areg[1];
        *(float4*)&f[8] = areg[2]; *(float4*)&f[12] = areg[3];
        v8s hv0, hv1, lv0, lv1;
#pragma unroll
        for (int i = 0; i < 16; i++) {
            unsigned short h = f2bf(f[i]);
            unsigned short lo = f2bf(f[i] - bf2f(h));
            if (i < 8) { hv0[i] = (short)h; lv0[i] = (short)lo; }
            else       { hv1[i - 8] = (short)h; lv1[i - 8] = (short)lo; }
        }
        int kg0 = chalf >> 3;                 // 0 or 2
        int L0 = (r & 15) | (kg0 << 4);
        int t = r >> 4;
        *(v8s*)&smem[(size_t)(t * 64 + L0) * 8]        = hv0;
        *(v8s*)&smem[(size_t)(t * 64 + L0 + 16) * 8]   = hv1;
        *(v8s*)&smem[8192 + (size_t)(t * 64 + L0) * 8]      = lv0;
        *(v8s*)&smem[8192 + (size_t)(t * 64 + L0 + 16) * 8] = lv1;
        __syncthreads();

        if (ks < 3) {  // prefetch next K-step's A while MFMAs run
            const float* An = Arow + (ks + 1) * 32;
#pragma unroll
            for (int c = 0; c < 4; c++) areg[c] = *(const float4*)(An + c * 4);
        }

        v8s ah[4], al[4], bh[4], bl[4];
#pragma unroll
        for (int mt = 0; mt < 4; mt++) {
            ah[mt] = *(const v8s*)&smem[(size_t)((wm * 4 + mt) * 64 + lane) * 8];
            al[mt] = *(const v8s*)&smem[8192 + (size_t)((wm * 4 + mt) * 64 + lane) * 8];
        }
#pragma unroll
        for (int nt = 0; nt < 4; nt++) {
            size_t bo = ((size_t)(ks * 8 + wn * 4 + nt) * 64 + lane) * 8;
            bh[nt] = *(const v8s*)(Whi + bo);
            bl[nt] = *(const v8s*)(Wlo + bo);
        }
#pragma unroll
        for (int mt = 0; mt < 4; mt++)
#pragma unroll
            for (int nt = 0; nt < 4; nt++) {
                acc[mt][nt] = __builtin_amdgcn_mfma_f32_16x16x32_bf16(ah[mt], bh[nt], acc[mt][nt], 0, 0, 0);
                acc[mt][nt] = __builtin_amdgcn_mfma_f32_16x16x32_bf16(al[mt], bh[nt], acc[mt][nt], 0, 0, 0);
                acc[mt][nt] = __builtin_amdgcn_mfma_f32_16x16x32_bf16(ah[mt], bl[nt], acc[mt][nt], 0, 0, 0);
            }
        __syncthreads();
    }

    // epilogue: C/D layout col=lane&15, row=(lane>>4)*4+reg; bounce via LDS
    // (stride 136 to break bank alignment), then coalesced bf16x8 stores.
#pragma unroll
    for (int mt = 0; mt < 4; mt++)
#pragma unroll
        for (int nt = 0; nt < 4; nt++) {
            int col_l = wn * 64 + nt * 16 + (lane & 15);
#pragma unroll
            for (int rg = 0; rg < 4; rg++) {
                int row_l = wm * 64 + mt * 16 + ((lane >> 4) << 2) + rg;
                smem[(size_t)row_l * 136 + col_l] = f2bf(acc[mt][nt][rg]);
            }
        }
    __syncthreads();
    int orow = tid >> 1;
    int ohalf = (tid & 1) * 64;
    const unsigned short* sp = &smem[(size_t)orow * 136 + ohalf];
    unsigned short* dp = Chw + (size_t)(row0 + orow) * FD + ohalf;
#pragma unroll
    for (int c = 0; c < 4; c++)
        *(v8s*)(dp + c * 8) = *(const v8s*)(sp + c * 8);
}

// ---------- sparse aggregation + bias + relu; one wave per node ----------
// hw is bf16 (4B/lane gather), accumulate fp32, output fp32.
__global__ __launch_bounds__(256) void k_agg(const unsigned short* __restrict__ hw,
                                             const int* __restrict__ offs,
                                             const int* __restrict__ col,
                                             const float* __restrict__ wgt,
                                             const float* __restrict__ dinv,
                                             const float* __restrict__ bias,
                                             float* __restrict__ hout) {
    int gw = (blockIdx.x * 256 + threadIdx.x) >> 6;
    int lane = threadIdx.x & 63;
    if (gw >= NN) return;
    float di = dinv[gw];
    ushort2 sv = *(const ushort2*)(hw + (size_t)gw * FD + lane * 2);
    float ax = di * di * bf2f(sv.x), ay = di * di * bf2f(sv.y);  // self loop
    int b = offs[gw], e = offs[gw + 1];
    for (int i = b; i < e; i++) {
        int s = col[i];
        float ww = wgt[i];
        ushort2 v = *(const ushort2*)(hw + (size_t)s * FD + lane * 2);
        ax += ww * bf2f(v.x);
        ay += ww * bf2f(v.y);
    }
    float2 bb = *(const float2*)(bias + lane * 2);
    ax += bb.x; ay += bb.y;
    ax = ax > 0.f ? ax : 0.f;
    ay = ay > 0.f ? ay : 0.f;
    *(float2*)(hout + (size_t)gw * FD + lane * 2) = make_float2(ax, ay);
}

// ---------- residual + classifier: out = (h + x) @ cls_w + cls_b ----------
__global__ __launch_bounds__(256) void k_cls(const float* __restrict__ h,
                                             const float* __restrict__ x,
                                             const float* __restrict__ cw,
                                             const float* __restrict__ cb,
                                             float* __restrict__ out) {
    int gw = (blockIdx.x * 256 + threadIdx.x) >> 6;
    int lane = threadIdx.x & 63;
    if (gw >= NN) return;
    float2 hv = *(const float2*)(h + (size_t)gw * FD + lane * 2);
    float2 xv = *(const float2*)(x + (size_t)gw * FD + lane * 2);
    float sx = hv.x + xv.x, sy = hv.y + xv.y;
    float4 w0 = *(const float4*)(cw + (lane * 2) * 4);
    float4 w1 = *(const float4*)(cw + (lane * 2 + 1) * 4);
    float p0 = sx * w0.x + sy * w1.x;
    float p1 = sx * w0.y + sy * w1.y;
    float p2 = sx * w0.z + sy * w1.z;
    float p3 = sx * w0.w + sy * w1.w;
#pragma unroll
    for (int off = 32; off > 0; off >>= 1) {
        p0 += __shfl_down(p0, off);
        p1 += __shfl_down(p1, off);
        p2 += __shfl_down(p2, off);
        p3 += __shfl_down(p3, off);
    }
    if (lane == 0) {
        float4 r2 = make_float4(p0 + cb[0], p1 + cb[1], p2 + cb[2], p3 + cb[3]);
        *(float4*)(out + (size_t)gw * 4) = r2;
    }
}

extern "C" void kernel_launch(void* const* d_in, const int* in_sizes, int n_in,
                              void* d_out, int out_size, void* d_ws, size_t ws_size,
                              hipStream_t stream) {
    const float* x       = (const float*)d_in[0];
    const int* ei        = (const int*)d_in[1];       // [2][EE], int32
    const float* weights = (const float*)d_in[2];     // [64][128][128]
    const float* biases  = (const float*)d_in[3];     // [64][128]
    const float* cls_w   = (const float*)d_in[4];     // [128][4]
    const float* cls_b   = (const float*)d_in[5];     // [4]
    float* out = (float*)d_out;

    char* ws = (char*)d_ws;
    size_t off = 0;
    auto alloc = [&](size_t bytes) -> void* {
        off = (off + 255) & ~(size_t)255;
        void* p = ws + off;
        off += bytes;
        return p;
    };
    int*   cnt    = (int*)alloc((size_t)NN * 4);
    int*   cursor = (int*)alloc((size_t)NN * 4);
    float* dinv   = (float*)alloc((size_t)NN * 4);
    int*   offs   = (int*)alloc((size_t)(NN + 1) * 4);
    int*   col    = (int*)alloc((size_t)EE * 4);
    float* wgt    = (float*)alloc((size_t)EE * 4);
    unsigned short* Whi = (unsigned short*)alloc((size_t)NL * FD * FD * 2);
    unsigned short* Wlo = (unsigned short*)alloc((size_t)NL * FD * FD * 2);
    unsigned short* chw = (unsigned short*)alloc((size_t)NN * FD * 2);
    float* h0     = (float*)alloc((size_t)NN * FD * 4);
    float* h1     = (float*)alloc((size_t)NN * FD * 4);

    const int* srcv = ei;
    const int* dstv = ei + EE;

    hipMemsetAsync(cnt, 0, (size_t)NN * 4, stream);
    hipMemsetAsync(cursor, 0, (size_t)NN * 4, stream);
    k_deg<<<EE / 256, 256, 0, stream>>>(dstv, cnt);
    k_dinv<<<NN / 256, 256, 0, stream>>>(cnt, dinv);
    k_scan<<<1, 1024, 0, stream>>>(cnt, offs);
    k_fill<<<EE / 256, 256, 0, stream>>>(srcv, dstv, dinv, offs, cursor, col, wgt);
    k_wsplit<<<NL * 2048 / 256, 256, 0, stream>>>(weights, Whi, Wlo);

    const float* hin = x;
    for (int l = 0; l < NL; l++) {
        float* hout = (l & 1) ? h1 : h0;
        k_gemm_mfma<<<NN / 128, 256, 0, stream>>>(hin, Whi + (size_t)l * FD * FD,
                                                  Wlo + (size_t)l * FD * FD, chw);
        k_agg<<<NN * 64 / 256, 256, 0, stream>>>(chw, offs, col, wgt, dinv,
                                                 biases + (size_t)l * FD, hout);
        hin = hout;
    }
    k_cls<<<NN * 64 / 256, 256, 0, stream>>>(hin, x, cls_w, cls_b, out);
}

// Round 4
// 2597.779 us; speedup vs baseline: 1.5639x; 1.1416x over previous
//
#include <hip/hip_runtime.h>
#include <hip/hip_bf16.h>

#define NN 32768
#define EE 262144
#define FD 128
#define NL 64

typedef short v8s __attribute__((ext_vector_type(8)));
typedef float v4f __attribute__((ext_vector_type(4)));

__device__ __forceinline__ unsigned short f2bf(float x) {
    unsigned u = __builtin_bit_cast(unsigned, x);
    u += 0x7fffu + ((u >> 16) & 1u);
    return (unsigned short)(u >> 16);
}
__device__ __forceinline__ float bf2f(unsigned short h) {
    unsigned u = ((unsigned)h) << 16;
    return __builtin_bit_cast(float, u);
}

// ---------- setup ----------
__global__ __launch_bounds__(256) void k_deg(const int* __restrict__ dst,
                                             int* __restrict__ cnt) {
    int e = blockIdx.x * 256 + threadIdx.x;
    if (e < EE) atomicAdd(&cnt[dst[e]], 1);
}

__global__ __launch_bounds__(256) void k_dinv(const int* __restrict__ cnt,
                                              float* __restrict__ dinv) {
    int i = blockIdx.x * 256 + threadIdx.x;
    if (i < NN) dinv[i] = rsqrtf((float)cnt[i] + 1.0f);
}

__global__ __launch_bounds__(1024) void k_scan(const int* __restrict__ cnt,
                                               int* __restrict__ offs) {
    __shared__ int wsum[16];
    int tid = threadIdx.x;
    int base = tid * 32;
    int local[32];
    int s = 0;
#pragma unroll
    for (int i = 0; i < 32; i++) { local[i] = s; s += cnt[base + i]; }
    int lane = tid & 63, wv = tid >> 6;
    int x = s;
#pragma unroll
    for (int off = 1; off < 64; off <<= 1) {
        int y = __shfl_up(x, off);
        if (lane >= off) x += y;
    }
    if (lane == 63) wsum[wv] = x;
    __syncthreads();
    if (tid == 0) {
        int t = 0;
        for (int i = 0; i < 16; i++) { int v = wsum[i]; wsum[i] = t; t += v; }
        offs[NN] = t;
    }
    __syncthreads();
    int excl = wsum[wv] + x - s;
#pragma unroll
    for (int i = 0; i < 32; i++) offs[base + i] = excl + local[i];
}

__global__ __launch_bounds__(256) void k_fill(const int* __restrict__ src,
                                              const int* __restrict__ dst,
                                              const float* __restrict__ dinv,
                                              const int* __restrict__ offs,
                                              int* __restrict__ cursor,
                                              int* __restrict__ col,
                                              float* __restrict__ wgt) {
    int e = blockIdx.x * 256 + threadIdx.x;
    if (e >= EE) return;
    int s = src[e], d = dst[e];
    int slot = atomicAdd(&cursor[d], 1);
    int p = offs[d] + slot;
    col[p] = s;
    wgt[p] = dinv[s] * dinv[d];
}

// x (fp32) -> hi/lo bf16 split, row-major
__global__ __launch_bounds__(256) void k_xsplit(const float* __restrict__ x,
                                                unsigned short* __restrict__ hi,
                                                unsigned short* __restrict__ lo) {
    int i = blockIdx.x * 256 + threadIdx.x;  // group of 4 elems
    float4 v = *(const float4*)(x + (size_t)i * 4);
    float f[4] = {v.x, v.y, v.z, v.w};
    ushort4 hv, lv;
    unsigned short* hp = (unsigned short*)&hv;
    unsigned short* lp = (unsigned short*)&lv;
#pragma unroll
    for (int j = 0; j < 4; j++) {
        unsigned short h = f2bf(f[j]);
        hp[j] = h;
        lp[j] = f2bf(f[j] - bf2f(h));
    }
    *(ushort4*)(hi + (size_t)i * 4) = hv;
    *(ushort4*)(lo + (size_t)i * 4) = lv;
}

// ---------- weight split: fp32 W -> bf16 hi/lo in MFMA B-fragment order ----
// [l][kstep(4)][ntile(8)][lane(64)][j(8)]; k = ks*32+(lane>>4)*8+j, n = nt*16+(lane&15)
__global__ __launch_bounds__(256) void k_wsplit(const float* __restrict__ W,
                                                unsigned short* __restrict__ Whi,
                                                unsigned short* __restrict__ Wlo) {
    int t = blockIdx.x * 256 + threadIdx.x;
    int l = t >> 11;
    int rem = t & 2047;
    int ks = rem >> 9;
    int rem2 = rem & 511;
    int nt = rem2 >> 6;
    int L = rem2 & 63;
    const float* Wl = W + (size_t)l * FD * FD;
    int kbase = ks * 32 + ((L >> 4) << 3);
    int n = nt * 16 + (L & 15);
    v8s hv, lv;
#pragma unroll
    for (int j = 0; j < 8; j++) {
        float w = Wl[(size_t)(kbase + j) * FD + n];
        unsigned short h = f2bf(w);
        hv[j] = (short)h;
        lv[j] = (short)f2bf(w - bf2f(h));
    }
    size_t o = (size_t)t * 8;
    *(v8s*)(Whi + o) = hv;
    *(v8s*)(Wlo + o) = lv;
}

// ---------- dense: Chw[bf16] = (Ahi+Alo) @ (Whi+Wlo), split-bf16 MFMA ------
// 32-row tile per block, grid=1024 (4 blocks/CU, 16 waves/CU). Wave w covers
// cols w*32..w*32+31: 2x2 tiles of 16x16x32, 3 MFMAs each (hh, lh, hl).
// No LDS / barriers in the K loop; A and B fragments load straight from
// global (A: L1/L2-hot rows; B: 128KB L2-resident per layer).
__global__ __launch_bounds__(256, 4) void k_gemm_mfma(
        const unsigned short* __restrict__ Ahi,
        const unsigned short* __restrict__ Alo,
        const unsigned short* __restrict__ Whi,
        const unsigned short* __restrict__ Wlo,
        unsigned short* __restrict__ Chw) {
    __shared__ unsigned short sme[32 * 136];  // epilogue only (8.7 KB)
    int tid = threadIdx.x;
    int lane = tid & 63;
    int w = tid >> 6;            // wave = col group w*32
    int row0 = blockIdx.x * 32;

    v4f acc[2][2];
#pragma unroll
    for (int i = 0; i < 2; i++)
#pragma unroll
        for (int j = 0; j < 2; j++) acc[i][j] = (v4f){0.f, 0.f, 0.f, 0.f};

#pragma unroll
    for (int ks = 0; ks < 4; ks++) {
        v8s ah[2], al[2], bh[2], bl[2];
#pragma unroll
        for (int mt = 0; mt < 2; mt++) {
            size_t ao = (size_t)(row0 + mt * 16 + (lane & 15)) * FD + ks * 32 + ((lane >> 4) << 3);
            ah[mt] = *(const v8s*)(Ahi + ao);
            al[mt] = *(const v8s*)(Alo + ao);
        }
#pragma unroll
        for (int nt = 0; nt < 2; nt++) {
            size_t bo = ((size_t)(ks * 8 + w * 2 + nt) * 64 + lane) * 8;
            bh[nt] = *(const v8s*)(Whi + bo);
            bl[nt] = *(const v8s*)(Wlo + bo);
        }
#pragma unroll
        for (int mt = 0; mt < 2; mt++)
#pragma unroll
            for (int nt = 0; nt < 2; nt++) {
                acc[mt][nt] = __builtin_amdgcn_mfma_f32_16x16x32_bf16(ah[mt], bh[nt], acc[mt][nt], 0, 0, 0);
                acc[mt][nt] = __builtin_amdgcn_mfma_f32_16x16x32_bf16(al[mt], bh[nt], acc[mt][nt], 0, 0, 0);
                acc[mt][nt] = __builtin_amdgcn_mfma_f32_16x16x32_bf16(ah[mt], bl[nt], acc[mt][nt], 0, 0, 0);
            }
    }

    // epilogue: C/D layout col=lane&15, row=(lane>>4)*4+reg; LDS bounce then
    // coalesced bf16x8 stores.
#pragma unroll
    for (int mt = 0; mt < 2; mt++)
#pragma unroll
        for (int nt = 0; nt < 2; nt++) {
            int col_l = w * 32 + nt * 16 + (lane & 15);
#pragma unroll
            for (int rg = 0; rg < 4; rg++) {
                int row_l = mt * 16 + ((lane >> 4) << 2) + rg;
                sme[row_l * 136 + col_l] = f2bf(acc[mt][nt][rg]);
            }
        }
    __syncthreads();
    int orow = tid >> 3;           // 0..31
    int ocol = (tid & 7) * 16;     // 0..112
    const unsigned short* sp = &sme[orow * 136 + ocol];
    unsigned short* dp = Chw + (size_t)(row0 + orow) * FD + ocol;
    *(v8s*)dp = *(const v8s*)sp;
    *(v8s*)(dp + 8) = *(const v8s*)(sp + 8);
}

// ---------- sparse aggregation + bias + relu; one wave per node ----------
// CSR slice loaded cooperatively (coalesced), broadcast via shfl; gather
// software-pipelined 1 deep. Output written as hi/lo bf16 split (the next
// layer's GEMM A operands) — split cost lives here, hidden by memory waits.
__global__ __launch_bounds__(256) void k_agg(const unsigned short* __restrict__ hw,
                                             const int* __restrict__ offs,
                                             const int* __restrict__ col,
                                             const float* __restrict__ wgt,
                                             const float* __restrict__ dinv,
                                             const float* __restrict__ bias,
                                             unsigned short* __restrict__ hhi,
                                             unsigned short* __restrict__ hlo) {
    int gw = (blockIdx.x * 256 + threadIdx.x) >> 6;
    int lane = threadIdx.x & 63;
    if (gw >= NN) return;
    float di = dinv[gw];
    ushort2 sv = *(const ushort2*)(hw + (size_t)gw * FD + lane * 2);
    float ax = di * di * bf2f(sv.x), ay = di * di * bf2f(sv.y);  // self loop
    int b = offs[gw], e = offs[gw + 1];
    int deg = e - b;
    for (int base = 0; base < deg; base += 64) {
        int n = min(deg - base, 64);
        int c = 0; float wv = 0.f;
        if (lane < n) {
            c = col[b + base + lane];
            wv = wgt[b + base + lane];
        }
        int s0 = __shfl(c, 0);
        float w0 = __shfl(wv, 0);
        ushort2 v0 = *(const ushort2*)(hw + (size_t)s0 * FD + lane * 2);
        for (int j = 1; j < n; j++) {
            int s1 = __shfl(c, j);
            float w1 = __shfl(wv, j);
            ushort2 v1 = *(const ushort2*)(hw + (size_t)s1 * FD + lane * 2);
            ax += w0 * bf2f(v0.x);
            ay += w0 * bf2f(v0.y);
            v0 = v1; w0 = w1;
        }
        ax += w0 * bf2f(v0.x);
        ay += w0 * bf2f(v0.y);
    }
    float2 bb = *(const float2*)(bias + lane * 2);
    ax += bb.x; ay += bb.y;
    ax = ax > 0.f ? ax : 0.f;
    ay = ay > 0.f ? ay : 0.f;
    unsigned short hx = f2bf(ax), hy = f2bf(ay);
    unsigned short lx = f2bf(ax - bf2f(hx)), ly = f2bf(ay - bf2f(hy));
    size_t o = (size_t)gw * FD + lane * 2;
    *(ushort2*)(hhi + o) = make_ushort2(hx, hy);
    *(ushort2*)(hlo + o) = make_ushort2(lx, ly);
}

// ---------- residual + classifier: out = (h + x) @ cls_w + cls_b ----------
__global__ __launch_bounds__(256) void k_cls(const unsigned short* __restrict__ hhi,
                                             const unsigned short* __restrict__ hlo,
                                             const float* __restrict__ x,
                                             const float* __restrict__ cw,
                                             const float* __restrict__ cb,
                                             float* __restrict__ out) {
    int gw = (blockIdx.x * 256 + threadIdx.x) >> 6;
    int lane = threadIdx.x & 63;
    if (gw >= NN) return;
    size_t o = (size_t)gw * FD + lane * 2;
    ushort2 hh = *(const ushort2*)(hhi + o);
    ushort2 ll = *(const ushort2*)(hlo + o);
    float2 xv = *(const float2*)(x + o);
    float sx = bf2f(hh.x) + bf2f(ll.x) + xv.x;
    float sy = bf2f(hh.y) + bf2f(ll.y) + xv.y;
    float4 w0 = *(const float4*)(cw + (lane * 2) * 4);
    float4 w1 = *(const float4*)(cw + (lane * 2 + 1) * 4);
    float p0 = sx * w0.x + sy * w1.x;
    float p1 = sx * w0.y + sy * w1.y;
    float p2 = sx * w0.z + sy * w1.z;
    float p3 = sx * w0.w + sy * w1.w;
#pragma unroll
    for (int off = 32; off > 0; off >>= 1) {
        p0 += __shfl_down(p0, off);
        p1 += __shfl_down(p1, off);
        p2 += __shfl_down(p2, off);
        p3 += __shfl_down(p3, off);
    }
    if (lane == 0) {
        float4 r2 = make_float4(p0 + cb[0], p1 + cb[1], p2 + cb[2], p3 + cb[3]);
        *(float4*)(out + (size_t)gw * 4) = r2;
    }
}

extern "C" void kernel_launch(void* const* d_in, const int* in_sizes, int n_in,
                              void* d_out, int out_size, void* d_ws, size_t ws_size,
                              hipStream_t stream) {
    const float* x       = (const float*)d_in[0];
    const int* ei        = (const int*)d_in[1];       // [2][EE], int32
    const float* weights = (const float*)d_in[2];
    const float* biases  = (const float*)d_in[3];
    const float* cls_w   = (const float*)d_in[4];
    const float* cls_b   = (const float*)d_in[5];
    float* out = (float*)d_out;

    char* ws = (char*)d_ws;
    size_t off = 0;
    auto alloc = [&](size_t bytes) -> void* {
        off = (off + 255) & ~(size_t)255;
        void* p = ws + off;
        off += bytes;
        return p;
    };
    int*   cnt    = (int*)alloc((size_t)NN * 4);
    int*   cursor = (int*)alloc((size_t)NN * 4);
    float* dinv   = (float*)alloc((size_t)NN * 4);
    int*   offs   = (int*)alloc((size_t)(NN + 1) * 4);
    int*   col    = (int*)alloc((size_t)EE * 4);
    float* wgt    = (float*)alloc((size_t)EE * 4);
    unsigned short* Whi = (unsigned short*)alloc((size_t)NL * FD * FD * 2);
    unsigned short* Wlo = (unsigned short*)alloc((size_t)NL * FD * FD * 2);
    unsigned short* chw = (unsigned short*)alloc((size_t)NN * FD * 2);
    unsigned short* h0hi = (unsigned short*)alloc((size_t)NN * FD * 2);
    unsigned short* h0lo = (unsigned short*)alloc((size_t)NN * FD * 2);
    unsigned short* h1hi = (unsigned short*)alloc((size_t)NN * FD * 2);
    unsigned short* h1lo = (unsigned short*)alloc((size_t)NN * FD * 2);

    const int* srcv = ei;
    const int* dstv = ei + EE;

    hipMemsetAsync(cnt, 0, (size_t)NN * 4, stream);
    hipMemsetAsync(cursor, 0, (size_t)NN * 4, stream);
    k_deg<<<EE / 256, 256, 0, stream>>>(dstv, cnt);
    k_dinv<<<NN / 256, 256, 0, stream>>>(cnt, dinv);
    k_scan<<<1, 1024, 0, stream>>>(cnt, offs);
    k_fill<<<EE / 256, 256, 0, stream>>>(srcv, dstv, dinv, offs, cursor, col, wgt);
    k_wsplit<<<NL * 2048 / 256, 256, 0, stream>>>(weights, Whi, Wlo);
    k_xsplit<<<NN * FD / 1024, 256, 0, stream>>>(x, h1hi, h1lo);  // x lives in h1 (free until l=1 writes it)

    const unsigned short* hinHi = h1hi;
    const unsigned short* hinLo = h1lo;
    for (int l = 0; l < NL; l++) {
        unsigned short* hoHi = (l & 1) ? h1hi : h0hi;
        unsigned short* hoLo = (l & 1) ? h1lo : h0lo;
        k_gemm_mfma<<<NN / 32, 256, 0, stream>>>(hinHi, hinLo,
                                                 Whi + (size_t)l * FD * FD,
                                                 Wlo + (size_t)l * FD * FD, chw);
        k_agg<<<NN * 64 / 256, 256, 0, stream>>>(chw, offs, col, wgt, dinv,
                                                 biases + (size_t)l * FD, hoHi, hoLo);
        hinHi = hoHi; hinLo = hoLo;
    }
    k_cls<<<NN * 64 / 256, 256, 0, stream>>>(hinHi, hinLo, x, cls_w, cls_b, out);
}

// Round 5
// 2287.253 us; speedup vs baseline: 1.7763x; 1.1358x over previous
//
#include <hip/hip_runtime.h>
#include <hip/hip_bf16.h>

#define NN 32768
#define EE 262144
#define FD 128
#define NL 64

typedef short v8s __attribute__((ext_vector_type(8)));
typedef float v4f __attribute__((ext_vector_type(4)));

__device__ __forceinline__ unsigned short f2bf(float x) {
    unsigned u = __builtin_bit_cast(unsigned, x);
    u += 0x7fffu + ((u >> 16) & 1u);
    return (unsigned short)(u >> 16);
}
__device__ __forceinline__ float bf2f(unsigned short h) {
    unsigned u = ((unsigned)h) << 16;
    return __builtin_bit_cast(float, u);
}

// ---------- setup ----------
__global__ __launch_bounds__(256) void k_deg(const int* __restrict__ dst,
                                             int* __restrict__ cnt) {
    int e = blockIdx.x * 256 + threadIdx.x;
    if (e < EE) atomicAdd(&cnt[dst[e]], 1);
}

__global__ __launch_bounds__(256) void k_dinv(const int* __restrict__ cnt,
                                              float* __restrict__ dinv) {
    int i = blockIdx.x * 256 + threadIdx.x;
    if (i < NN) dinv[i] = rsqrtf((float)cnt[i] + 1.0f);
}

__global__ __launch_bounds__(1024) void k_scan(const int* __restrict__ cnt,
                                               int* __restrict__ offs) {
    __shared__ int wsum[16];
    int tid = threadIdx.x;
    int base = tid * 32;
    int local[32];
    int s = 0;
#pragma unroll
    for (int i = 0; i < 32; i++) { local[i] = s; s += cnt[base + i]; }
    int lane = tid & 63, wv = tid >> 6;
    int x = s;
#pragma unroll
    for (int off = 1; off < 64; off <<= 1) {
        int y = __shfl_up(x, off);
        if (lane >= off) x += y;
    }
    if (lane == 63) wsum[wv] = x;
    __syncthreads();
    if (tid == 0) {
        int t = 0;
        for (int i = 0; i < 16; i++) { int v = wsum[i]; wsum[i] = t; t += v; }
        offs[NN] = t;
    }
    __syncthreads();
    int excl = wsum[wv] + x - s;
#pragma unroll
    for (int i = 0; i < 32; i++) offs[base + i] = excl + local[i];
}

__global__ __launch_bounds__(256) void k_fill(const int* __restrict__ src,
                                              const int* __restrict__ dst,
                                              const int* __restrict__ offs,
                                              int* __restrict__ cursor,
                                              int* __restrict__ col) {
    int e = blockIdx.x * 256 + threadIdx.x;
    if (e >= EE) return;
    int s = src[e], d = dst[e];
    int slot = atomicAdd(&cursor[d], 1);
    col[offs[d] + slot] = s;
}

// x (fp32) -> bf16 cast, row-major (8 elems/thread)
__global__ __launch_bounds__(256) void k_xcast(const float* __restrict__ x,
                                               unsigned short* __restrict__ h) {
    int i = blockIdx.x * 256 + threadIdx.x;
    float4 a = *(const float4*)(x + (size_t)i * 8);
    float4 b = *(const float4*)(x + (size_t)i * 8 + 4);
    v8s o;
    o[0] = (short)f2bf(a.x); o[1] = (short)f2bf(a.y);
    o[2] = (short)f2bf(a.z); o[3] = (short)f2bf(a.w);
    o[4] = (short)f2bf(b.x); o[5] = (short)f2bf(b.y);
    o[6] = (short)f2bf(b.z); o[7] = (short)f2bf(b.w);
    *(v8s*)(h + (size_t)i * 8) = o;
}

// ---------- weight split: fp32 W -> bf16 hi/lo in MFMA B-fragment order ----
// [l][kstep(4)][ntile(8)][lane(64)][j(8)]; k = ks*32+(lane>>4)*8+j, n = nt*16+(lane&15)
__global__ __launch_bounds__(256) void k_wsplit(const float* __restrict__ W,
                                                unsigned short* __restrict__ Whi,
                                                unsigned short* __restrict__ Wlo) {
    int t = blockIdx.x * 256 + threadIdx.x;
    int l = t >> 11;
    int rem = t & 2047;
    int ks = rem >> 9;
    int rem2 = rem & 511;
    int nt = rem2 >> 6;
    int L = rem2 & 63;
    const float* Wl = W + (size_t)l * FD * FD;
    int kbase = ks * 32 + ((L >> 4) << 3);
    int n = nt * 16 + (L & 15);
    v8s hv, lv;
#pragma unroll
    for (int j = 0; j < 8; j++) {
        float w = Wl[(size_t)(kbase + j) * FD + n];
        unsigned short h = f2bf(w);
        hv[j] = (short)h;
        lv[j] = (short)f2bf(w - bf2f(h));
    }
    size_t o = (size_t)t * 8;
    *(v8s*)(Whi + o) = hv;
    *(v8s*)(Wlo + o) = lv;
}

// ---------- dense: Chw[bf16] = dinv * (A @ (Whi+Wlo)), bf16 MFMA ----------
// A is bf16 (h). 32-row tile per block, grid=1024 (4 blocks/CU). Wave w
// covers cols w*32..+31: 2x2 tiles of 16x16x32, 2 MFMAs each (A*Wh, A*Wl).
// Epilogue scales row r by dinv[r] so the aggregation is a plain sum.
__global__ __launch_bounds__(256, 4) void k_gemm_mfma(
        const unsigned short* __restrict__ Ah,
        const unsigned short* __restrict__ Whi,
        const unsigned short* __restrict__ Wlo,
        const float* __restrict__ dinv,
        unsigned short* __restrict__ Chw) {
    __shared__ unsigned short sme[32 * 136];  // epilogue only (8.7 KB)
    int tid = threadIdx.x;
    int lane = tid & 63;
    int w = tid >> 6;
    int row0 = blockIdx.x * 32;

    v4f acc[2][2];
#pragma unroll
    for (int i = 0; i < 2; i++)
#pragma unroll
        for (int j = 0; j < 2; j++) acc[i][j] = (v4f){0.f, 0.f, 0.f, 0.f};

#pragma unroll
    for (int ks = 0; ks < 4; ks++) {
        v8s ah[2], bh[2], bl[2];
#pragma unroll
        for (int mt = 0; mt < 2; mt++) {
            size_t ao = (size_t)(row0 + mt * 16 + (lane & 15)) * FD + ks * 32 + ((lane >> 4) << 3);
            ah[mt] = *(const v8s*)(Ah + ao);
        }
#pragma unroll
        for (int nt = 0; nt < 2; nt++) {
            size_t bo = ((size_t)(ks * 8 + w * 2 + nt) * 64 + lane) * 8;
            bh[nt] = *(const v8s*)(Whi + bo);
            bl[nt] = *(const v8s*)(Wlo + bo);
        }
#pragma unroll
        for (int mt = 0; mt < 2; mt++)
#pragma unroll
            for (int nt = 0; nt < 2; nt++) {
                acc[mt][nt] = __builtin_amdgcn_mfma_f32_16x16x32_bf16(ah[mt], bh[nt], acc[mt][nt], 0, 0, 0);
                acc[mt][nt] = __builtin_amdgcn_mfma_f32_16x16x32_bf16(ah[mt], bl[nt], acc[mt][nt], 0, 0, 0);
            }
    }

    // epilogue: C/D layout col=lane&15, row=(lane>>4)*4+reg; scale by dinv,
    // LDS bounce, coalesced bf16x8 stores.
#pragma unroll
    for (int mt = 0; mt < 2; mt++)
#pragma unroll
        for (int nt = 0; nt < 2; nt++) {
            int col_l = w * 32 + nt * 16 + (lane & 15);
#pragma unroll
            for (int rg = 0; rg < 4; rg++) {
                int row_l = mt * 16 + ((lane >> 4) << 2) + rg;
                sme[row_l * 136 + col_l] = f2bf(acc[mt][nt][rg] * dinv[row0 + row_l]);
            }
        }
    __syncthreads();
    int orow = tid >> 3;
    int ocol = (tid & 7) * 16;
    const unsigned short* sp = &sme[orow * 136 + ocol];
    unsigned short* dp = Chw + (size_t)(row0 + orow) * FD + ocol;
    *(v8s*)dp = *(const v8s*)sp;
    *(v8s*)(dp + 8) = *(const v8s*)(sp + 8);
}

// ---------- sparse aggregation + bias + relu; one wave per node ----------
// chw is dinv-scaled, so aggregation = dinv[dst] * (sum of gathered rows +
// own row) + bias. Gather is software-pipelined 4 deep (4 loads in flight).
__global__ __launch_bounds__(256) void k_agg(const unsigned short* __restrict__ chw,
                                             const int* __restrict__ offs,
                                             const int* __restrict__ col,
                                             const float* __restrict__ dinv,
                                             const float* __restrict__ bias,
                                             unsigned short* __restrict__ hout) {
    int gw = (blockIdx.x * 256 + threadIdx.x) >> 6;
    int lane = threadIdx.x & 63;
    size_t lo2 = (size_t)lane * 2;
    ushort2 sv = *(const ushort2*)(chw + (size_t)gw * FD + lo2);
    float ax = bf2f(sv.x), ay = bf2f(sv.y);  // self loop (dinv folded in)
    int b = offs[gw], e = offs[gw + 1];
    int deg = e - b;
    for (int base = 0; base < deg; base += 64) {
        int n = min(deg - base, 64);
        int c = 0;
        if (lane < n) c = col[b + base + lane];
        ushort2 v0, v1, v2, v3;
        if (n > 0) v0 = *(const ushort2*)(chw + (size_t)__shfl(c, 0) * FD + lo2);
        if (n > 1) v1 = *(const ushort2*)(chw + (size_t)__shfl(c, 1) * FD + lo2);
        if (n > 2) v2 = *(const ushort2*)(chw + (size_t)__shfl(c, 2) * FD + lo2);
        if (n > 3) v3 = *(const ushort2*)(chw + (size_t)__shfl(c, 3) * FD + lo2);
        int j = 0;
        for (; j + 4 < n; j++) {
            ax += bf2f(v0.x); ay += bf2f(v0.y);
            v0 = v1; v1 = v2; v2 = v3;
            v3 = *(const ushort2*)(chw + (size_t)__shfl(c, j + 4) * FD + lo2);
        }
        int k = n - j;
        if (k > 0) { ax += bf2f(v0.x); ay += bf2f(v0.y); }
        if (k > 1) { ax += bf2f(v1.x); ay += bf2f(v1.y); }
        if (k > 2) { ax += bf2f(v2.x); ay += bf2f(v2.y); }
        if (k > 3) { ax += bf2f(v3.x); ay += bf2f(v3.y); }
    }
    float di = dinv[gw];
    float2 bb = *(const float2*)(bias + lane * 2);
    ax = di * ax + bb.x;
    ay = di * ay + bb.y;
    ax = fmaxf(ax, 0.f);
    ay = fmaxf(ay, 0.f);
    *(ushort2*)(hout + (size_t)gw * FD + lo2) = make_ushort2(f2bf(ax), f2bf(ay));
}

// ---------- residual + classifier: out = (h + x) @ cls_w + cls_b ----------
__global__ __launch_bounds__(256) void k_cls(const unsigned short* __restrict__ h,
                                             const float* __restrict__ x,
                                             const float* __restrict__ cw,
                                             const float* __restrict__ cb,
                                             float* __restrict__ out) {
    int gw = (blockIdx.x * 256 + threadIdx.x) >> 6;
    int lane = threadIdx.x & 63;
    size_t o = (size_t)gw * FD + lane * 2;
    ushort2 hh = *(const ushort2*)(h + o);
    float2 xv = *(const float2*)(x + o);
    float sx = bf2f(hh.x) + xv.x;
    float sy = bf2f(hh.y) + xv.y;
    float4 w0 = *(const float4*)(cw + (lane * 2) * 4);
    float4 w1 = *(const float4*)(cw + (lane * 2 + 1) * 4);
    float p0 = sx * w0.x + sy * w1.x;
    float p1 = sx * w0.y + sy * w1.y;
    float p2 = sx * w0.z + sy * w1.z;
    float p3 = sx * w0.w + sy * w1.w;
#pragma unroll
    for (int off = 32; off > 0; off >>= 1) {
        p0 += __shfl_down(p0, off);
        p1 += __shfl_down(p1, off);
        p2 += __shfl_down(p2, off);
        p3 += __shfl_down(p3, off);
    }
    if (lane == 0) {
        float4 r2 = make_float4(p0 + cb[0], p1 + cb[1], p2 + cb[2], p3 + cb[3]);
        *(float4*)(out + (size_t)gw * 4) = r2;
    }
}

extern "C" void kernel_launch(void* const* d_in, const int* in_sizes, int n_in,
                              void* d_out, int out_size, void* d_ws, size_t ws_size,
                              hipStream_t stream) {
    const float* x       = (const float*)d_in[0];
    const int* ei        = (const int*)d_in[1];       // [2][EE], int32
    const float* weights = (const float*)d_in[2];
    const float* biases  = (const float*)d_in[3];
    const float* cls_w   = (const float*)d_in[4];
    const float* cls_b   = (const float*)d_in[5];
    float* out = (float*)d_out;

    char* ws = (char*)d_ws;
    size_t off = 0;
    auto alloc = [&](size_t bytes) -> void* {
        off = (off + 255) & ~(size_t)255;
        void* p = ws + off;
        off += bytes;
        return p;
    };
    int*   cnt    = (int*)alloc((size_t)NN * 4);
    int*   cursor = (int*)alloc((size_t)NN * 4);
    float* dinv   = (float*)alloc((size_t)NN * 4);
    int*   offs   = (int*)alloc((size_t)(NN + 1) * 4);
    int*   col    = (int*)alloc((size_t)EE * 4);
    unsigned short* Whi = (unsigned short*)alloc((size_t)NL * FD * FD * 2);
    unsigned short* Wlo = (unsigned short*)alloc((size_t)NL * FD * FD * 2);
    unsigned short* chw = (unsigned short*)alloc((size_t)NN * FD * 2);
    unsigned short* h0  = (unsigned short*)alloc((size_t)NN * FD * 2);
    unsigned short* h1  = (unsigned short*)alloc((size_t)NN * FD * 2);

    const int* srcv = ei;
    const int* dstv = ei + EE;

    hipMemsetAsync(cnt, 0, (size_t)NN * 4, stream);
    hipMemsetAsync(cursor, 0, (size_t)NN * 4, stream);
    k_deg<<<EE / 256, 256, 0, stream>>>(dstv, cnt);
    k_dinv<<<NN / 256, 256, 0, stream>>>(cnt, dinv);
    k_scan<<<1, 1024, 0, stream>>>(cnt, offs);
    k_fill<<<EE / 256, 256, 0, stream>>>(srcv, dstv, offs, cursor, col);
    k_wsplit<<<NL * 2048 / 256, 256, 0, stream>>>(weights, Whi, Wlo);
    k_xcast<<<NN * FD / 2048, 256, 0, stream>>>(x, h1);  // x lives in h1 (free until l=1)

    const unsigned short* hin = h1;
    for (int l = 0; l < NL; l++) {
        unsigned short* hout = (l & 1) ? h1 : h0;
        k_gemm_mfma<<<NN / 32, 256, 0, stream>>>(hin, Whi + (size_t)l * FD * FD,
                                                 Wlo + (size_t)l * FD * FD, dinv, chw);
        k_agg<<<NN * 64 / 256, 256, 0, stream>>>(chw, offs, col, dinv,
                                                 biases + (size_t)l * FD, hout);
        hin = hout;
    }
    k_cls<<<NN * 64 / 256, 256, 0, stream>>>(hin, x, cls_w, cls_b, out);
}

// Round 6
// 2251.383 us; speedup vs baseline: 1.8046x; 1.0159x over previous
//
#include <hip/hip_runtime.h>
#include <hip/hip_bf16.h>

#define NN 32768
#define EE 262144
#define FD 128
#define NL 64

typedef short v8s __attribute__((ext_vector_type(8)));
typedef float v4f __attribute__((ext_vector_type(4)));

__device__ __forceinline__ unsigned short f2bf(float x) {
    unsigned u = __builtin_bit_cast(unsigned, x);
    u += 0x7fffu + ((u >> 16) & 1u);
    return (unsigned short)(u >> 16);
}
__device__ __forceinline__ float bf2f(unsigned short h) {
    unsigned u = ((unsigned)h) << 16;
    return __builtin_bit_cast(float, u);
}

// ---------- setup ----------
__global__ __launch_bounds__(256) void k_deg(const int* __restrict__ dst,
                                             int* __restrict__ cnt) {
    int e = blockIdx.x * 256 + threadIdx.x;
    if (e < EE) atomicAdd(&cnt[dst[e]], 1);
}

__global__ __launch_bounds__(256) void k_dinv(const int* __restrict__ cnt,
                                              float* __restrict__ dinv) {
    int i = blockIdx.x * 256 + threadIdx.x;
    if (i < NN) dinv[i] = rsqrtf((float)cnt[i] + 1.0f);
}

__global__ __launch_bounds__(1024) void k_scan(const int* __restrict__ cnt,
                                               int* __restrict__ offs) {
    __shared__ int wsum[16];
    int tid = threadIdx.x;
    int base = tid * 32;
    int local[32];
    int s = 0;
#pragma unroll
    for (int i = 0; i < 32; i++) { local[i] = s; s += cnt[base + i]; }
    int lane = tid & 63, wv = tid >> 6;
    int x = s;
#pragma unroll
    for (int off = 1; off < 64; off <<= 1) {
        int y = __shfl_up(x, off);
        if (lane >= off) x += y;
    }
    if (lane == 63) wsum[wv] = x;
    __syncthreads();
    if (tid == 0) {
        int t = 0;
        for (int i = 0; i < 16; i++) { int v = wsum[i]; wsum[i] = t; t += v; }
        offs[NN] = t;
    }
    __syncthreads();
    int excl = wsum[wv] + x - s;
#pragma unroll
    for (int i = 0; i < 32; i++) offs[base + i] = excl + local[i];
}

__global__ __launch_bounds__(256) void k_fill(const int* __restrict__ src,
                                              const int* __restrict__ dst,
                                              const int* __restrict__ offs,
                                              int* __restrict__ cursor,
                                              int* __restrict__ col) {
    int e = blockIdx.x * 256 + threadIdx.x;
    if (e >= EE) return;
    int s = src[e], d = dst[e];
    int slot = atomicAdd(&cursor[d], 1);
    col[offs[d] + slot] = s;
}

// g0 = bf16(dinv[node] * x), row-major (8 elems/thread, all in one node row)
__global__ __launch_bounds__(256) void k_xcast(const float* __restrict__ x,
                                               const float* __restrict__ dinv,
                                               unsigned short* __restrict__ g) {
    int i = blockIdx.x * 256 + threadIdx.x;
    float di = dinv[(i * 8) >> 7];
    float4 a = *(const float4*)(x + (size_t)i * 8);
    float4 b = *(const float4*)(x + (size_t)i * 8 + 4);
    v8s o;
    o[0] = (short)f2bf(di * a.x); o[1] = (short)f2bf(di * a.y);
    o[2] = (short)f2bf(di * a.z); o[3] = (short)f2bf(di * a.w);
    o[4] = (short)f2bf(di * b.x); o[5] = (short)f2bf(di * b.y);
    o[6] = (short)f2bf(di * b.z); o[7] = (short)f2bf(di * b.w);
    *(v8s*)(g + (size_t)i * 8) = o;
}

// ---------- weight split: fp32 W -> bf16 hi/lo in MFMA B-fragment order ----
// [l][kstep(4)][ntile(8)][lane(64)][j(8)]; k = ks*32+(lane>>4)*8+j, n = nt*16+(lane&15)
__global__ __launch_bounds__(256) void k_wsplit(const float* __restrict__ W,
                                                unsigned short* __restrict__ Whi,
                                                unsigned short* __restrict__ Wlo) {
    int t = blockIdx.x * 256 + threadIdx.x;
    int l = t >> 11;
    int rem = t & 2047;
    int ks = rem >> 9;
    int rem2 = rem & 511;
    int nt = rem2 >> 6;
    int L = rem2 & 63;
    const float* Wl = W + (size_t)l * FD * FD;
    int kbase = ks * 32 + ((L >> 4) << 3);
    int n = nt * 16 + (L & 15);
    v8s hv, lv;
#pragma unroll
    for (int j = 0; j < 8; j++) {
        float w = Wl[(size_t)(kbase + j) * FD + n];
        unsigned short h = f2bf(w);
        hv[j] = (short)h;
        lv[j] = (short)f2bf(w - bf2f(h));
    }
    size_t o = (size_t)t * 8;
    *(v8s*)(Whi + o) = hv;
    *(v8s*)(Wlo + o) = lv;
}

// ---------- fused layer: g_out = dinv * relu( (dinv*(sum g)) @ W + b ) ----
// Uses A(HW) = (AH)W: aggregate first, then MFMA transform, one kernel.
// Block = 32 nodes, 4 waves; wave aggregates 8 nodes into LDS tile, then
// GEMM phase: wave w covers cols w*32..+31, 2x2 MFMA tiles, W in hi/lo bf16.
#define SROW 132   // LDS tile stride (ushorts): frag reads 4-way, writes free
__global__ __launch_bounds__(256, 4) void k_layer(
        const unsigned short* __restrict__ g,
        const int* __restrict__ offs,
        const int* __restrict__ col,
        const unsigned short* __restrict__ Whi,
        const unsigned short* __restrict__ Wlo,
        const float* __restrict__ dinv,
        const float* __restrict__ bias,
        unsigned short* __restrict__ gout,
        int last) {
    __shared__ unsigned short sA[32 * SROW];
    __shared__ float sDinv[32];
    int tid = threadIdx.x;
    int lane = tid & 63;
    int w = tid >> 6;
    int row0 = blockIdx.x * 32;
    size_t lo2 = (size_t)lane * 2;

    if (tid < 32) sDinv[tid] = dinv[row0 + tid];

    // phase 1: aggregate 8 nodes per wave (4-deep pipelined gather)
    for (int r = 0; r < 8; r++) {
        int nloc = w * 8 + r;
        int node = row0 + nloc;
        ushort2 sv = *(const ushort2*)(g + (size_t)node * FD + lo2);
        float ax = bf2f(sv.x), ay = bf2f(sv.y);  // self loop
        int b = offs[node], e = offs[node + 1];
        int deg = e - b;
        for (int base = 0; base < deg; base += 64) {
            int n = min(deg - base, 64);
            int c = 0;
            if (lane < n) c = col[b + base + lane];
            ushort2 v0, v1, v2, v3;
            if (n > 0) v0 = *(const ushort2*)(g + (size_t)__shfl(c, 0) * FD + lo2);
            if (n > 1) v1 = *(const ushort2*)(g + (size_t)__shfl(c, 1) * FD + lo2);
            if (n > 2) v2 = *(const ushort2*)(g + (size_t)__shfl(c, 2) * FD + lo2);
            if (n > 3) v3 = *(const ushort2*)(g + (size_t)__shfl(c, 3) * FD + lo2);
            int j = 0;
            for (; j + 4 < n; j++) {
                ax += bf2f(v0.x); ay += bf2f(v0.y);
                v0 = v1; v1 = v2; v2 = v3;
                v3 = *(const ushort2*)(g + (size_t)__shfl(c, j + 4) * FD + lo2);
            }
            int k = n - j;
            if (k > 0) { ax += bf2f(v0.x); ay += bf2f(v0.y); }
            if (k > 1) { ax += bf2f(v1.x); ay += bf2f(v1.y); }
            if (k > 2) { ax += bf2f(v2.x); ay += bf2f(v2.y); }
            if (k > 3) { ax += bf2f(v3.x); ay += bf2f(v3.y); }
        }
        float di = dinv[node];
        // A row = dinv[node] * (sum of g) = row of (A_hat H); store bf16
        *(ushort2*)&sA[nloc * SROW + lane * 2] =
            make_ushort2(f2bf(di * ax), f2bf(di * ay));
    }
    __syncthreads();

    // phase 2: 32x128 @ 128x128 MFMA (A from LDS, W hi/lo from L2)
    v4f acc[2][2];
#pragma unroll
    for (int i = 0; i < 2; i++)
#pragma unroll
        for (int j = 0; j < 2; j++) acc[i][j] = (v4f){0.f, 0.f, 0.f, 0.f};

#pragma unroll
    for (int ks = 0; ks < 4; ks++) {
        v8s ah[2], bh[2], bl[2];
#pragma unroll
        for (int mt = 0; mt < 2; mt++)
            ah[mt] = *(const v8s*)&sA[(mt * 16 + (lane & 15)) * SROW + ks * 32 + ((lane >> 4) << 3)];
#pragma unroll
        for (int nt = 0; nt < 2; nt++) {
            size_t bo = ((size_t)(ks * 8 + w * 2 + nt) * 64 + lane) * 8;
            bh[nt] = *(const v8s*)(Whi + bo);
            bl[nt] = *(const v8s*)(Wlo + bo);
        }
#pragma unroll
        for (int mt = 0; mt < 2; mt++)
#pragma unroll
            for (int nt = 0; nt < 2; nt++) {
                acc[mt][nt] = __builtin_amdgcn_mfma_f32_16x16x32_bf16(ah[mt], bh[nt], acc[mt][nt], 0, 0, 0);
                acc[mt][nt] = __builtin_amdgcn_mfma_f32_16x16x32_bf16(ah[mt], bl[nt], acc[mt][nt], 0, 0, 0);
            }
    }
    __syncthreads();  // before reusing sA for the epilogue

    // epilogue: bias + relu (+ dinv scale unless last layer), LDS bounce,
    // coalesced bf16 stores. C/D layout: col=lane&15, row=(lane>>4)*4+reg.
    float bb0 = bias[w * 32 + (lane & 15)];
    float bb1 = bias[w * 32 + 16 + (lane & 15)];
#pragma unroll
    for (int mt = 0; mt < 2; mt++)
#pragma unroll
        for (int nt = 0; nt < 2; nt++) {
            int col_l = w * 32 + nt * 16 + (lane & 15);
            float bb = nt ? bb1 : bb0;
#pragma unroll
            for (int rg = 0; rg < 4; rg++) {
                int row_l = mt * 16 + ((lane >> 4) << 2) + rg;
                float v = fmaxf(acc[mt][nt][rg] + bb, 0.f);
                if (!last) v *= sDinv[row_l];
                sA[row_l * SROW + col_l] = f2bf(v);
            }
        }
    __syncthreads();
    int orow = tid >> 3;
    int ocol = (tid & 7) * 16;
    const unsigned short* sp = &sA[orow * SROW + ocol];
    unsigned short* dp = gout + (size_t)(row0 + orow) * FD + ocol;
    *(v8s*)dp = *(const v8s*)sp;
    *(v8s*)(dp + 8) = *(const v8s*)(sp + 8);
}

// ---------- residual + classifier: out = (h + x) @ cls_w + cls_b ----------
__global__ __launch_bounds__(256) void k_cls(const unsigned short* __restrict__ h,
                                             const float* __restrict__ x,
                                             const float* __restrict__ cw,
                                             const float* __restrict__ cb,
                                             float* __restrict__ out) {
    int gw = (blockIdx.x * 256 + threadIdx.x) >> 6;
    int lane = threadIdx.x & 63;
    size_t o = (size_t)gw * FD + lane * 2;
    ushort2 hh = *(const ushort2*)(h + o);
    float2 xv = *(const float2*)(x + o);
    float sx = bf2f(hh.x) + xv.x;
    float sy = bf2f(hh.y) + xv.y;
    float4 w0 = *(const float4*)(cw + (lane * 2) * 4);
    float4 w1 = *(const float4*)(cw + (lane * 2 + 1) * 4);
    float p0 = sx * w0.x + sy * w1.x;
    float p1 = sx * w0.y + sy * w1.y;
    float p2 = sx * w0.z + sy * w1.z;
    float p3 = sx * w0.w + sy * w1.w;
#pragma unroll
    for (int off = 32; off > 0; off >>= 1) {
        p0 += __shfl_down(p0, off);
        p1 += __shfl_down(p1, off);
        p2 += __shfl_down(p2, off);
        p3 += __shfl_down(p3, off);
    }
    if (lane == 0) {
        float4 r2 = make_float4(p0 + cb[0], p1 + cb[1], p2 + cb[2], p3 + cb[3]);
        *(float4*)(out + (size_t)gw * 4) = r2;
    }
}

extern "C" void kernel_launch(void* const* d_in, const int* in_sizes, int n_in,
                              void* d_out, int out_size, void* d_ws, size_t ws_size,
                              hipStream_t stream) {
    const float* x       = (const float*)d_in[0];
    const int* ei        = (const int*)d_in[1];       // [2][EE], int32
    const float* weights = (const float*)d_in[2];
    const float* biases  = (const float*)d_in[3];
    const float* cls_w   = (const float*)d_in[4];
    const float* cls_b   = (const float*)d_in[5];
    float* out = (float*)d_out;

    char* ws = (char*)d_ws;
    size_t off = 0;
    auto alloc = [&](size_t bytes) -> void* {
        off = (off + 255) & ~(size_t)255;
        void* p = ws + off;
        off += bytes;
        return p;
    };
    int*   cnt    = (int*)alloc((size_t)NN * 4);
    int*   cursor = (int*)alloc((size_t)NN * 4);
    float* dinv   = (float*)alloc((size_t)NN * 4);
    int*   offs   = (int*)alloc((size_t)(NN + 1) * 4);
    int*   col    = (int*)alloc((size_t)EE * 4);
    unsigned short* Whi = (unsigned short*)alloc((size_t)NL * FD * FD * 2);
    unsigned short* Wlo = (unsigned short*)alloc((size_t)NL * FD * FD * 2);
    unsigned short* h0  = (unsigned short*)alloc((size_t)NN * FD * 2);
    unsigned short* h1  = (unsigned short*)alloc((size_t)NN * FD * 2);

    const int* srcv = ei;
    const int* dstv = ei + EE;

    hipMemsetAsync(cnt, 0, (size_t)NN * 4, stream);
    hipMemsetAsync(cursor, 0, (size_t)NN * 4, stream);
    k_deg<<<EE / 256, 256, 0, stream>>>(dstv, cnt);
    k_dinv<<<NN / 256, 256, 0, stream>>>(cnt, dinv);
    k_scan<<<1, 1024, 0, stream>>>(cnt, offs);
    k_fill<<<EE / 256, 256, 0, stream>>>(srcv, dstv, offs, cursor, col);
    k_wsplit<<<NL * 2048 / 256, 256, 0, stream>>>(weights, Whi, Wlo);
    k_xcast<<<NN * FD / 2048, 256, 0, stream>>>(x, dinv, h1);  // g0 in h1

    const unsigned short* gin = h1;
    for (int l = 0; l < NL; l++) {
        unsigned short* gout = (l & 1) ? h1 : h0;
        k_layer<<<NN / 32, 256, 0, stream>>>(gin, offs, col,
                                             Whi + (size_t)l * FD * FD,
                                             Wlo + (size_t)l * FD * FD,
                                             dinv, biases + (size_t)l * FD,
                                             gout, l == NL - 1);
        gin = gout;
    }
    k_cls<<<NN * 64 / 256, 256, 0, stream>>>(gin, x, cls_w, cls_b, out);
}

// Round 7
// 1269.670 us; speedup vs baseline: 3.1999x; 1.7732x over previous
//
#include <hip/hip_runtime.h>
#include <hip/hip_bf16.h>

#define NN 32768
#define EE 262144
#define FD 128
#define NL 64
#define MROW 16     // nodes per block
#define SROW 132    // LDS row stride (ushorts)

typedef short v8s __attribute__((ext_vector_type(8)));
typedef float v4f __attribute__((ext_vector_type(4)));

__device__ __forceinline__ unsigned short f2bf(float x) {
    unsigned u = __builtin_bit_cast(unsigned, x);
    u += 0x7fffu + ((u >> 16) & 1u);
    return (unsigned short)(u >> 16);
}
__device__ __forceinline__ float bf2f(unsigned short h) {
    unsigned u = ((unsigned)h) << 16;
    return __builtin_bit_cast(float, u);
}
// accumulate 8 bf16 (packed in v8s) into acc[8]
__device__ __forceinline__ void acc8_bf16(float* acc, v8s r) {
    const int* d = (const int*)&r;
#pragma unroll
    for (int k = 0; k < 4; k++) {
        unsigned u = (unsigned)d[k];
        acc[2 * k]     += __builtin_bit_cast(float, u << 16);
        acc[2 * k + 1] += __builtin_bit_cast(float, u & 0xffff0000u);
    }
}

// ---------- setup ----------
__global__ __launch_bounds__(256) void k_deg(const int* __restrict__ dst,
                                             int* __restrict__ cnt) {
    int e = blockIdx.x * 256 + threadIdx.x;
    if (e < EE) atomicAdd(&cnt[dst[e]], 1);
}

__global__ __launch_bounds__(256) void k_dinv(const int* __restrict__ cnt,
                                              float* __restrict__ dinv) {
    int i = blockIdx.x * 256 + threadIdx.x;
    if (i < NN) dinv[i] = rsqrtf((float)cnt[i] + 1.0f);
}

__global__ __launch_bounds__(1024) void k_scan(const int* __restrict__ cnt,
                                               int* __restrict__ offs) {
    __shared__ int wsum[16];
    int tid = threadIdx.x;
    int base = tid * 32;
    int local[32];
    int s = 0;
#pragma unroll
    for (int i = 0; i < 32; i++) { local[i] = s; s += cnt[base + i]; }
    int lane = tid & 63, wv = tid >> 6;
    int x = s;
#pragma unroll
    for (int off = 1; off < 64; off <<= 1) {
        int y = __shfl_up(x, off);
        if (lane >= off) x += y;
    }
    if (lane == 63) wsum[wv] = x;
    __syncthreads();
    if (tid == 0) {
        int t = 0;
        for (int i = 0; i < 16; i++) { int v = wsum[i]; wsum[i] = t; t += v; }
        offs[NN] = t;
    }
    __syncthreads();
    int excl = wsum[wv] + x - s;
#pragma unroll
    for (int i = 0; i < 32; i++) offs[base + i] = excl + local[i];
}

__global__ __launch_bounds__(256) void k_fill(const int* __restrict__ src,
                                              const int* __restrict__ dst,
                                              const int* __restrict__ offs,
                                              int* __restrict__ cursor,
                                              int* __restrict__ col) {
    int e = blockIdx.x * 256 + threadIdx.x;
    if (e >= EE) return;
    int s = src[e], d = dst[e];
    int slot = atomicAdd(&cursor[d], 1);
    col[offs[d] + slot] = s;
}

// g0 = bf16(dinv[node] * x)
__global__ __launch_bounds__(256) void k_xcast(const float* __restrict__ x,
                                               const float* __restrict__ dinv,
                                               unsigned short* __restrict__ g) {
    int i = blockIdx.x * 256 + threadIdx.x;
    float di = dinv[(i * 8) >> 7];
    float4 a = *(const float4*)(x + (size_t)i * 8);
    float4 b = *(const float4*)(x + (size_t)i * 8 + 4);
    v8s o;
    o[0] = (short)f2bf(di * a.x); o[1] = (short)f2bf(di * a.y);
    o[2] = (short)f2bf(di * a.z); o[3] = (short)f2bf(di * a.w);
    o[4] = (short)f2bf(di * b.x); o[5] = (short)f2bf(di * b.y);
    o[6] = (short)f2bf(di * b.z); o[7] = (short)f2bf(di * b.w);
    *(v8s*)(g + (size_t)i * 8) = o;
}

// ---------- weight split: fp32 W -> bf16 hi/lo in MFMA B-fragment order ----
// [l][kstep(4)][ntile(8)][lane(64)][j(8)]; k = ks*32+(lane>>4)*8+j, n = nt*16+(lane&15)
__global__ __launch_bounds__(256) void k_wsplit(const float* __restrict__ W,
                                                unsigned short* __restrict__ Whi,
                                                unsigned short* __restrict__ Wlo) {
    int t = blockIdx.x * 256 + threadIdx.x;
    int l = t >> 11;
    int rem = t & 2047;
    int ks = rem >> 9;
    int rem2 = rem & 511;
    int nt = rem2 >> 6;
    int L = rem2 & 63;
    const float* Wl = W + (size_t)l * FD * FD;
    int kbase = ks * 32 + ((L >> 4) << 3);
    int n = nt * 16 + (L & 15);
    v8s hv, lv;
#pragma unroll
    for (int j = 0; j < 8; j++) {
        float w = Wl[(size_t)(kbase + j) * FD + n];
        unsigned short h = f2bf(w);
        hv[j] = (short)h;
        lv[j] = (short)f2bf(w - bf2f(h));
    }
    size_t o = (size_t)t * 8;
    *(v8s*)(Whi + o) = hv;
    *(v8s*)(Wlo + o) = lv;
}

// ---------- fused layer: g_out = dinv * relu( (dinv*(sum g)) @ W + b ) ----
// Phase 1: gather — 16 lanes/edge x 4 edge-groups, dwordx4 loads, 2-deep
// unroll (8 edges in flight, no register rotation). Phase 2: M=16 MFMA.
// Grid = NN/16 = 2048 blocks -> 8 blocks/CU, 32 waves/CU.
__global__ __launch_bounds__(256, 8) void k_layer(
        const unsigned short* __restrict__ g,
        const int* __restrict__ offs,
        const int* __restrict__ col,
        const unsigned short* __restrict__ Whi,
        const unsigned short* __restrict__ Wlo,
        const float* __restrict__ dinv,
        const float* __restrict__ bias,
        unsigned short* __restrict__ gout,
        int last) {
    __shared__ unsigned short sA[MROW * SROW];
    __shared__ float sDinv[MROW];
    int tid = threadIdx.x;
    int lane = tid & 63;
    int w = tid >> 6;
    int row0 = blockIdx.x * MROW;
    int fg = lane >> 4;        // edge subgroup 0..3
    int fl = lane & 15;        // feature chunk (8 feats)
    const unsigned short* gf = g + fl * 8;

    if (tid < MROW) sDinv[tid] = dinv[row0 + tid];

    // phase 1: each wave aggregates 4 nodes
    for (int r = 0; r < 4; r++) {
        int nloc = w * 4 + r;
        int node = row0 + nloc;
        float acc[8];
#pragma unroll
        for (int k = 0; k < 8; k++) acc[k] = 0.f;
        int b = offs[node], e = offs[node + 1];
        int deg = e - b;
        for (int base = 0; base < deg; base += 64) {
            int n = min(deg - base, 64);
            int c = (lane < n) ? col[b + base + lane] : 0;
            for (int j = 0; j < n; j += 8) {
                int e0 = j + fg, e1 = j + 4 + fg;
                int s0 = __shfl(c, e0 & 63);
                int s1 = __shfl(c, e1 & 63);
                bool p0 = e0 < n, p1 = e1 < n;
                v8s r0, r1;
                if (p0) r0 = *(const v8s*)(gf + (size_t)s0 * FD);
                if (p1) r1 = *(const v8s*)(gf + (size_t)s1 * FD);
                if (p0) acc8_bf16(acc, r0);
                if (p1) acc8_bf16(acc, r1);
            }
        }
        // reduce the 4 edge subgroups
#pragma unroll
        for (int k = 0; k < 8; k++) {
            acc[k] += __shfl_xor(acc[k], 16);
            acc[k] += __shfl_xor(acc[k], 32);
        }
        // self loop (g already dinv-scaled)
        v8s sv = *(const v8s*)(gf + (size_t)node * FD);
        acc8_bf16(acc, sv);
        float di = dinv[node];
        if (fg == 0) {  // lanes 0..15 hold/write the full row
            unsigned pk[4];
#pragma unroll
            for (int k = 0; k < 4; k++) {
                unsigned lo = f2bf(di * acc[2 * k]);
                unsigned hi = f2bf(di * acc[2 * k + 1]);
                pk[k] = lo | (hi << 16);
            }
            *(v8s*)&sA[nloc * SROW + fl * 8] = *(v8s*)pk;
        }
    }
    __syncthreads();

    // phase 2: 16x128 @ 128x128 MFMA (A from LDS, W hi/lo from L2)
    v4f a0 = (v4f){0.f, 0.f, 0.f, 0.f};
    v4f a1 = (v4f){0.f, 0.f, 0.f, 0.f};
#pragma unroll
    for (int ks = 0; ks < 4; ks++) {
        v8s ah = *(const v8s*)&sA[(lane & 15) * SROW + ks * 32 + ((lane >> 4) << 3)];
        size_t bo0 = ((size_t)(ks * 8 + w * 2) * 64 + lane) * 8;
        size_t bo1 = ((size_t)(ks * 8 + w * 2 + 1) * 64 + lane) * 8;
        v8s bh0 = *(const v8s*)(Whi + bo0);
        v8s bl0 = *(const v8s*)(Wlo + bo0);
        v8s bh1 = *(const v8s*)(Whi + bo1);
        v8s bl1 = *(const v8s*)(Wlo + bo1);
        a0 = __builtin_amdgcn_mfma_f32_16x16x32_bf16(ah, bh0, a0, 0, 0, 0);
        a0 = __builtin_amdgcn_mfma_f32_16x16x32_bf16(ah, bl0, a0, 0, 0, 0);
        a1 = __builtin_amdgcn_mfma_f32_16x16x32_bf16(ah, bh1, a1, 0, 0, 0);
        a1 = __builtin_amdgcn_mfma_f32_16x16x32_bf16(ah, bl1, a1, 0, 0, 0);
    }
    __syncthreads();  // before reusing sA

    // epilogue: bias + relu (+ dinv unless last), LDS bounce, coalesced store
    float bb0 = bias[w * 32 + (lane & 15)];
    float bb1 = bias[w * 32 + 16 + (lane & 15)];
#pragma unroll
    for (int nt = 0; nt < 2; nt++) {
        int col_l = w * 32 + nt * 16 + (lane & 15);
        float bb = nt ? bb1 : bb0;
        v4f a = nt ? a1 : a0;
#pragma unroll
        for (int rg = 0; rg < 4; rg++) {
            int row_l = ((lane >> 4) << 2) + rg;
            float v = fmaxf(a[rg] + bb, 0.f);
            if (!last) v *= sDinv[row_l];
            sA[row_l * SROW + col_l] = f2bf(v);
        }
    }
    __syncthreads();
    int orow = tid >> 4;
    int ocol = (tid & 15) * 8;
    *(v8s*)(gout + (size_t)(row0 + orow) * FD + ocol) =
        *(const v8s*)&sA[orow * SROW + ocol];
}

// ---------- residual + classifier: out = (h + x) @ cls_w + cls_b ----------
__global__ __launch_bounds__(256) void k_cls(const unsigned short* __restrict__ h,
                                             const float* __restrict__ x,
                                             const float* __restrict__ cw,
                                             const float* __restrict__ cb,
                                             float* __restrict__ out) {
    int gw = (blockIdx.x * 256 + threadIdx.x) >> 6;
    int lane = threadIdx.x & 63;
    size_t o = (size_t)gw * FD + lane * 2;
    ushort2 hh = *(const ushort2*)(h + o);
    float2 xv = *(const float2*)(x + o);
    float sx = bf2f(hh.x) + xv.x;
    float sy = bf2f(hh.y) + xv.y;
    float4 w0 = *(const float4*)(cw + (lane * 2) * 4);
    float4 w1 = *(const float4*)(cw + (lane * 2 + 1) * 4);
    float p0 = sx * w0.x + sy * w1.x;
    float p1 = sx * w0.y + sy * w1.y;
    float p2 = sx * w0.z + sy * w1.z;
    float p3 = sx * w0.w + sy * w1.w;
#pragma unroll
    for (int off = 32; off > 0; off >>= 1) {
        p0 += __shfl_down(p0, off);
        p1 += __shfl_down(p1, off);
        p2 += __shfl_down(p2, off);
        p3 += __shfl_down(p3, off);
    }
    if (lane == 0) {
        float4 r2 = make_float4(p0 + cb[0], p1 + cb[1], p2 + cb[2], p3 + cb[3]);
        *(float4*)(out + (size_t)gw * 4) = r2;
    }
}

extern "C" void kernel_launch(void* const* d_in, const int* in_sizes, int n_in,
                              void* d_out, int out_size, void* d_ws, size_t ws_size,
                              hipStream_t stream) {
    const float* x       = (const float*)d_in[0];
    const int* ei        = (const int*)d_in[1];       // [2][EE], int32
    const float* weights = (const float*)d_in[2];
    const float* biases  = (const float*)d_in[3];
    const float* cls_w   = (const float*)d_in[4];
    const float* cls_b   = (const float*)d_in[5];
    float* out = (float*)d_out;

    char* ws = (char*)d_ws;
    size_t off = 0;
    auto alloc = [&](size_t bytes) -> void* {
        off = (off + 255) & ~(size_t)255;
        void* p = ws + off;
        off += bytes;
        return p;
    };
    int*   cnt    = (int*)alloc((size_t)NN * 4);
    int*   cursor = (int*)alloc((size_t)NN * 4);
    float* dinv   = (float*)alloc((size_t)NN * 4);
    int*   offs   = (int*)alloc((size_t)(NN + 1) * 4);
    int*   col    = (int*)alloc((size_t)EE * 4);
    unsigned short* Whi = (unsigned short*)alloc((size_t)NL * FD * FD * 2);
    unsigned short* Wlo = (unsigned short*)alloc((size_t)NL * FD * FD * 2);
    unsigned short* h0  = (unsigned short*)alloc((size_t)NN * FD * 2);
    unsigned short* h1  = (unsigned short*)alloc((size_t)NN * FD * 2);

    const int* srcv = ei;
    const int* dstv = ei + EE;

    hipMemsetAsync(cnt, 0, (size_t)NN * 4, stream);
    hipMemsetAsync(cursor, 0, (size_t)NN * 4, stream);
    k_deg<<<EE / 256, 256, 0, stream>>>(dstv, cnt);
    k_dinv<<<NN / 256, 256, 0, stream>>>(cnt, dinv);
    k_scan<<<1, 1024, 0, stream>>>(cnt, offs);
    k_fill<<<EE / 256, 256, 0, stream>>>(srcv, dstv, offs, cursor, col);
    k_wsplit<<<NL * 2048 / 256, 256, 0, stream>>>(weights, Whi, Wlo);
    k_xcast<<<NN * FD / 2048, 256, 0, stream>>>(x, dinv, h1);  // g0 in h1

    const unsigned short* gin = h1;
    for (int l = 0; l < NL; l++) {
        unsigned short* gout = (l & 1) ? h1 : h0;
        k_layer<<<NN / MROW, 256, 0, stream>>>(gin, offs, col,
                                               Whi + (size_t)l * FD * FD,
                                               Wlo + (size_t)l * FD * FD,
                                               dinv, biases + (size_t)l * FD,
                                               gout, l == NL - 1);
        gin = gout;
    }
    k_cls<<<NN * 64 / 256, 256, 0, stream>>>(gin, x, cls_w, cls_b, out);
}